// Round 3
// baseline (169.608 us; speedup 1.0000x reference)
//
#include <hip/hip_runtime.h>
#include <math.h>

// FNO 2D spectral conv, MI355X. B=8,H=256,W=256,CIN=COUT=32,M1=M2=16.
// R3: lane-mapping rework. K1: [w][c] LDS + scalar conflict-free reads +
// w0-twiddle decomposition + shfl reduce. K5: w-major lanes (full-BW twiddle
// reads, broadcast g reads, float4 stores). K2 split 4x over h (partials),
// K3 sums partials + float4 weight loads + i-split, K4 sums K3 partials.

#define INV_HW (1.0f / 65536.0f)

// ------------------------------------------------------------- twiddle gen
// Eo[ws2][w1 16][kwq4][8]: (cos,-sin) of 2pi*kw*(ws*64+4w1)/256, kw=4kwq+j
// Ei[kwq4][w0 4][8]:       (cos,-sin) of 2pi*kw*w0/256
// U [n 256] float2:        (cos, sin) of +2pi*n/256
// E4[w 128][q 8] float4:   (sce*ce, sce*se, sco*co, sco*so), +angle, kw=2q,2q+1
__global__ void k_tw(float* __restrict__ Eo, float* __restrict__ Ei,
                     float* __restrict__ U, float* __restrict__ E4) {
  int t = blockIdx.x * blockDim.x + threadIdx.x;
  const float step = 6.28318530717958647692f / 256.0f;
  if (t < 512) {
    int j = t & 3, kwq = (t >> 2) & 3, w1 = (t >> 4) & 15, ws = t >> 8;
    int kw = 4 * kwq + j, w = ws * 64 + 4 * w1;
    int m = (kw * w) & 255;
    float s, c; sincosf(step * (float)m, &s, &c);
    int base = ((ws * 16 + w1) * 4 + kwq) * 8 + 2 * j;
    Eo[base] = c; Eo[base + 1] = -s;
  } else if (t < 576) {
    int i = t - 512;
    int j = i & 3, w0 = (i >> 2) & 3, kwq = i >> 4;
    int kw = 4 * kwq + j;
    int m = (kw * w0) & 255;
    float s, c; sincosf(step * (float)m, &s, &c);
    int base = (kwq * 4 + w0) * 8 + 2 * j;
    Ei[base] = c; Ei[base + 1] = -s;
  } else if (t < 832) {
    int n = t - 576;
    float s, c; sincosf(step * (float)n, &s, &c);
    ((float2*)U)[n] = make_float2(c, s);
  } else if (t < 1856) {
    int i = t - 832;
    int w = i >> 3, q = i & 7;
    int me = (2 * q * w) & 255, mo = ((2 * q + 1) * w) & 255;
    float se, ce, so, co;
    sincosf(step * (float)me, &se, &ce);
    sincosf(step * (float)mo, &so, &co);
    float sc_e = (q == 0) ? INV_HW : 2.0f * INV_HW;
    float sc_o = 2.0f * INV_HW;
    ((float4*)E4)[i] = make_float4(sc_e * ce, sc_e * se, sc_o * co, sc_o * so);
  }
}

// ------------------------------------------------- K1: w-DFT  x -> T
// block=(b,h) 2048. Thread t = kwq*64 + ws*32 + c. T layout [bh][c][kw][2].
__global__ __launch_bounds__(256) void k_wdft(const float* __restrict__ x,
                                              const float* __restrict__ Eo,
                                              const float* __restrict__ Ei,
                                              float* __restrict__ T) {
  __shared__ __align__(16) float sx[8192];   // [w][c] linear, 32 KB
  __shared__ __align__(16) float sEo[1024];  // 4 KB
  __shared__ __align__(16) float sEi[128];
  int bh = blockIdx.x, t = threadIdx.x;
  const float4* src = (const float4*)(x + (size_t)bh * 8192);
  float4* dx = (float4*)sx;
#pragma unroll
  for (int i = 0; i < 8; ++i) dx[t + 256 * i] = src[t + 256 * i];
  ((float4*)sEo)[t] = ((const float4*)Eo)[t];
  if (t < 32) ((float4*)sEi)[t] = ((const float4*)Ei)[t];
  __syncthreads();
  int kwq = t >> 6, ws = (t >> 5) & 1, c = t & 31;
  float ar[4][4], ai[4][4];
#pragma unroll
  for (int a = 0; a < 4; ++a)
#pragma unroll
    for (int b = 0; b < 4; ++b) { ar[a][b] = 0.f; ai[a][b] = 0.f; }
  const float* xc = sx + c;
#pragma unroll 4
  for (int w1 = 0; w1 < 16; ++w1) {
    int wb = ws * 64 + 4 * w1;
    float xa0 = xc[(wb + 0) * 32], xa1 = xc[(wb + 1) * 32];
    float xa2 = xc[(wb + 2) * 32], xa3 = xc[(wb + 3) * 32];
    float xb0 = xc[(wb + 128) * 32], xb1 = xc[(wb + 129) * 32];
    float xb2 = xc[(wb + 130) * 32], xb3 = xc[(wb + 131) * 32];
    const float4* ep = (const float4*)(sEo + ((ws * 16 + w1) * 4 + kwq) * 8);
    float4 e01 = ep[0], e23 = ep[1];
    float ye, yo;
    ye = xa0 + xb0; yo = xa0 - xb0;
    ar[0][0] += ye * e01.x; ai[0][0] += ye * e01.y;
    ar[0][1] += yo * e01.z; ai[0][1] += yo * e01.w;
    ar[0][2] += ye * e23.x; ai[0][2] += ye * e23.y;
    ar[0][3] += yo * e23.z; ai[0][3] += yo * e23.w;
    ye = xa1 + xb1; yo = xa1 - xb1;
    ar[1][0] += ye * e01.x; ai[1][0] += ye * e01.y;
    ar[1][1] += yo * e01.z; ai[1][1] += yo * e01.w;
    ar[1][2] += ye * e23.x; ai[1][2] += ye * e23.y;
    ar[1][3] += yo * e23.z; ai[1][3] += yo * e23.w;
    ye = xa2 + xb2; yo = xa2 - xb2;
    ar[2][0] += ye * e01.x; ai[2][0] += ye * e01.y;
    ar[2][1] += yo * e01.z; ai[2][1] += yo * e01.w;
    ar[2][2] += ye * e23.x; ai[2][2] += ye * e23.y;
    ar[2][3] += yo * e23.z; ai[2][3] += yo * e23.w;
    ye = xa3 + xb3; yo = xa3 - xb3;
    ar[3][0] += ye * e01.x; ai[3][0] += ye * e01.y;
    ar[3][1] += yo * e01.z; ai[3][1] += yo * e01.w;
    ar[3][2] += ye * e23.x; ai[3][2] += ye * e23.y;
    ar[3][3] += yo * e23.z; ai[3][3] += yo * e23.w;
  }
  const float4* eip = (const float4*)(sEi + kwq * 32);
  float Tr[4] = {0, 0, 0, 0}, Ti[4] = {0, 0, 0, 0};
#pragma unroll
  for (int w0 = 0; w0 < 4; ++w0) {
    float4 g01 = eip[2 * w0], g23 = eip[2 * w0 + 1];
    Tr[0] += ar[w0][0] * g01.x - ai[w0][0] * g01.y;
    Ti[0] += ar[w0][0] * g01.y + ai[w0][0] * g01.x;
    Tr[1] += ar[w0][1] * g01.z - ai[w0][1] * g01.w;
    Ti[1] += ar[w0][1] * g01.w + ai[w0][1] * g01.z;
    Tr[2] += ar[w0][2] * g23.x - ai[w0][2] * g23.y;
    Ti[2] += ar[w0][2] * g23.y + ai[w0][2] * g23.x;
    Tr[3] += ar[w0][3] * g23.z - ai[w0][3] * g23.w;
    Ti[3] += ar[w0][3] * g23.w + ai[w0][3] * g23.z;
  }
#pragma unroll
  for (int j = 0; j < 4; ++j) {
    Tr[j] += __shfl_xor(Tr[j], 32);
    Ti[j] += __shfl_xor(Ti[j], 32);
  }
  if (ws == 0) {
    float* tp = T + (size_t)bh * 1024 + c * 32 + kwq * 8;
    *(float4*)tp = make_float4(Tr[0], Ti[0], Tr[1], Ti[1]);
    *(float4*)(tp + 4) = make_float4(Tr[2], Ti[2], Tr[3], Ti[3]);
  }
}

// ------------------------------------------------- K2: h-DFT  T -> Xp
// grid (b,c,hq)=1024. Partial sums over 32 folded h-pairs per block.
__global__ __launch_bounds__(256) void k_hdft(const float* __restrict__ T,
                                              const float* __restrict__ U,
                                              float* __restrict__ Xp) {
  __shared__ __align__(16) float sT[2048];  // [row 64][kw][2], 8 KB
  __shared__ float2 sU[256];
  int bi = blockIdx.x;
  int b = bi >> 7, c = (bi >> 2) & 31, hq = bi & 3;
  int t = threadIdx.x;
#pragma unroll
  for (int it = 0; it < 2; ++it) {
    int idx = t + 256 * it;
    int row = idx >> 3, col = idx & 7;
    int h = hq * 32 + (row & 31) + (row >> 5) * 128;
    ((float4*)sT)[idx] =
        *(const float4*)(T + (size_t)(b * 256 + h) * 1024 + c * 32 + col * 4);
  }
  sU[t] = ((const float2*)U)[t];
  __syncthreads();
  int khp = t >> 4, kw = t & 15;
  int kha2 = khp + 240;
  float sg = (khp & 1) ? -1.f : 1.f;
  int f0 = hq * 32;
  int ph1 = (khp * f0) & 255, ph2 = (kha2 * f0) & 255;
  float x0r = 0, x0i = 0, x1r = 0, x1i = 0;
#pragma unroll 4
  for (int fl = 0; fl < 32; ++fl) {
    float2 t0 = *(const float2*)(sT + fl * 32 + kw * 2);
    float2 t1 = *(const float2*)(sT + (fl + 32) * 32 + kw * 2);
    float tpx = fmaf(sg, t1.x, t0.x);
    float tpy = fmaf(sg, t1.y, t0.y);
    float2 e1 = sU[ph1], e2 = sU[ph2];
    x0r += tpx * e1.x + tpy * e1.y;
    x0i += tpy * e1.x - tpx * e1.y;
    x1r += tpx * e2.x + tpy * e2.y;
    x1i += tpy * e2.x - tpx * e2.y;
    ph1 = (ph1 + khp) & 255;
    ph2 = (ph2 + kha2) & 255;
  }
  float2* xb = (float2*)(Xp + (size_t)(hq * 256 + b * 32 + c) * 1024);
  xb[khp * 16 + kw] = make_float2(x0r, x0i);
  xb[(khp + 16) * 16 + kw] = make_float2(x1r, x1i);
}

// ------------------------------------------------- K3: channel mix Xp -> Yp
// grid (b,kh,ih)=512. Sums 4 hq-partials at load; i split across ih blocks +
// is lanes (shfl reduce). Thread t = o*8 + kwq*2 + is.
__global__ __launch_bounds__(256) void k_mix(const float* __restrict__ Xp,
                                             const float* __restrict__ wr,
                                             const float* __restrict__ wi_,
                                             float* __restrict__ Yp) {
  __shared__ __align__(16) float sX[1024];  // [i][kw][2]
  int bi = blockIdx.x;
  int b = bi >> 6, kh = (bi >> 1) & 31, ih = bi & 1;
  int blk = kh >> 4, khl = kh & 15;
  int t = threadIdx.x;
  {
    float4 acc = make_float4(0.f, 0.f, 0.f, 0.f);
#pragma unroll
    for (int hq = 0; hq < 4; ++hq) {
      float4 v = *(const float4*)(Xp + (size_t)(hq * 256 + b * 32 + (t >> 3)) * 1024 +
                                  kh * 32 + (t & 7) * 4);
      acc.x += v.x; acc.y += v.y; acc.z += v.z; acc.w += v.w;
    }
    ((float4*)sX)[t] = acc;
  }
  __syncthreads();
  int o = t >> 3, kwq = (t >> 1) & 3, is = t & 1;
  float yr[4] = {0, 0, 0, 0}, yi[4] = {0, 0, 0, 0};
  size_t wbase = (size_t)blk * 262144 + (size_t)o * 256 + khl * 16 + kwq * 4;
#pragma unroll
  for (int ii = 0; ii < 8; ++ii) {
    int i = ih * 16 + is * 8 + ii;
    float4 a = *(const float4*)(wr + wbase + (size_t)i * 8192);
    float4 bb = *(const float4*)(wi_ + wbase + (size_t)i * 8192);
    float4 x01 = *(const float4*)(sX + i * 32 + kwq * 8);
    float4 x23 = *(const float4*)(sX + i * 32 + kwq * 8 + 4);
    yr[0] += x01.x * a.x - x01.y * bb.x; yi[0] += x01.x * bb.x + x01.y * a.x;
    yr[1] += x01.z * a.y - x01.w * bb.y; yi[1] += x01.z * bb.y + x01.w * a.y;
    yr[2] += x23.x * a.z - x23.y * bb.z; yi[2] += x23.x * bb.z + x23.y * a.z;
    yr[3] += x23.z * a.w - x23.w * bb.w; yi[3] += x23.z * bb.w + x23.w * a.w;
  }
#pragma unroll
  for (int j = 0; j < 4; ++j) {
    yr[j] += __shfl_xor(yr[j], 1);
    yi[j] += __shfl_xor(yi[j], 1);
  }
  if (is == 0) {
    float* yp = Yp + (size_t)((ih * 8 + b) * 32 + o) * 1024 + kh * 32 + kwq * 8;
    *(float4*)yp = make_float4(yr[0], yi[0], yr[1], yi[1]);
    *(float4*)(yp + 4) = make_float4(yr[2], yi[2], yr[3], yi[3]);
  }
}

// ------------------------------------------------- K4: h-IDFT  Yp -> G
// grid (b,o,hc)=1024. Sums K3's 2 ih-partials at load. Radix-2: h & h+128.
__global__ __launch_bounds__(256) void k_hidft(const float* __restrict__ Yp,
                                               const float* __restrict__ U,
                                               float* __restrict__ G) {
  __shared__ __align__(16) float4 sY4[256];  // [kh][kwpair] 4 KB
  __shared__ float2 sU[256];
  int bi = blockIdx.x;
  int b = bi >> 7, o = (bi >> 2) & 31, hc = bi & 3;
  int t = threadIdx.x;
  {
    float4 va = ((const float4*)(Yp + (size_t)(b * 32 + o) * 1024))[t];
    float4 vb = ((const float4*)(Yp + (size_t)(256 + b * 32 + o) * 1024))[t];
    sY4[t] = make_float4(va.x + vb.x, va.y + vb.y, va.z + vb.z, va.w + vb.w);
  }
  sU[t] = ((const float2*)U)[t];
  __syncthreads();
  int q = t & 7, hl = t >> 3;
  int h = hc * 32 + hl;
  float se0r = 0, se0i = 0, se1r = 0, se1i = 0;
  float so0r = 0, so0i = 0, so1r = 0, so1i = 0;
#pragma unroll 4
  for (int kh2 = 0; kh2 < 16; ++kh2) {
    int khe = 2 * kh2, kho = khe + 1;
    int khae = khe < 16 ? khe : khe + 224;
    int khao = kho < 16 ? kho : kho + 224;
    float2 ee = sU[(khae * h) & 255];
    float2 eo = sU[(khao * h) & 255];
    float4 yE = sY4[khe * 8 + q];
    float4 yO = sY4[kho * 8 + q];
    se0r += yE.x * ee.x - yE.y * ee.y;
    se0i += yE.x * ee.y + yE.y * ee.x;
    se1r += yE.z * ee.x - yE.w * ee.y;
    se1i += yE.z * ee.y + yE.w * ee.x;
    so0r += yO.x * eo.x - yO.y * eo.y;
    so0i += yO.x * eo.y + yO.y * eo.x;
    so1r += yO.z * eo.x - yO.w * eo.y;
    so1i += yO.z * eo.y + yO.w * eo.x;
  }
  float* g0 = G + (((size_t)b * 256 + h) * 32 + o) * 32 + 4 * q;
  float* g1 = G + (((size_t)b * 256 + h + 128) * 32 + o) * 32 + 4 * q;
  *(float4*)g0 = make_float4(se0r + so0r, se0i + so0i, se1r + so1r, se1i + so1i);
  *(float4*)g1 = make_float4(se0r - so0r, se0i - so0i, se1r - so1r, se1i - so1i);
}

// ------------------------------------------------- K5: w-IDFT (c2r) G -> out
// block=(b,h) 2048. Thread t = og*128 + w: w-major lanes.
__global__ __launch_bounds__(256) void k_widft(const float* __restrict__ G,
                                               const float* __restrict__ E4,
                                               float* __restrict__ out) {
  __shared__ __align__(16) float sG[1024];   // [o][kw][2]
  __shared__ __align__(16) float4 sE4[1024]; // 16 KB
  int bh = blockIdx.x, t = threadIdx.x;
  ((float4*)sG)[t] = ((const float4*)(G + (size_t)bh * 1024))[t];
  const float4* e4g = (const float4*)E4;
#pragma unroll
  for (int i = 0; i < 4; ++i) sE4[t + 256 * i] = e4g[t + 256 * i];
  __syncthreads();
  int og = t >> 7, w = t & 127;
  float4 tw[8];
#pragma unroll
  for (int q = 0; q < 8; ++q) tw[q] = sE4[w * 8 + q];
  float* ob = out + (size_t)bh * 8192 + w * 32 + og * 16;
  float* ob2 = ob + 128 * 32;
#pragma unroll
  for (int g4 = 0; g4 < 4; ++g4) {
    float s0[4], s1[4];
#pragma unroll
    for (int k = 0; k < 4; ++k) {
      int o = og * 16 + g4 * 4 + k;
      const float4* gp = (const float4*)(sG + o * 32);
      float se = 0.f, so = 0.f;
#pragma unroll
      for (int q = 0; q < 8; ++q) {
        float4 g = gp[q];
        se += g.x * tw[q].x - g.y * tw[q].y;
        so += g.z * tw[q].z - g.w * tw[q].w;
      }
      s0[k] = se + so;
      s1[k] = se - so;
    }
    *(float4*)(ob + g4 * 4) = make_float4(s0[0], s0[1], s0[2], s0[3]);
    *(float4*)(ob2 + g4 * 4) = make_float4(s1[0], s1[1], s1[2], s1[3]);
  }
}

extern "C" void kernel_launch(void* const* d_in, const int* in_sizes, int n_in,
                              void* d_out, int out_size, void* d_ws, size_t ws_size,
                              hipStream_t stream) {
  const float* x = (const float*)d_in[0];   // [8,256,256,32]
  const float* wr = (const float*)d_in[1];  // [2,32,32,16,16]
  const float* wi = (const float*)d_in[2];
  float* out = (float*)d_out;               // [8,256,256,32]
  float* ws = (float*)d_ws;

  float* Eo = ws;            // 1024 f
  float* Ei = ws + 1024;     // 128 f (pad to 256)
  float* U  = ws + 1280;     // 512 f
  float* E4 = ws + 1792;     // 4096 f
  float* T  = ws + 6144;     // 2097152 f  [bh][c][kw][2]
  float* Xp = ws + 2103296;  // 1048576 f  [hq4][b*32+c][kh][kw][2]
  float* Yp = ws + 3151872;  // 524288 f   [ih2][b][o][kh][kw][2]
  float* G  = T;             // reuse (T dead after K2)

  k_tw<<<8, 256, 0, stream>>>(Eo, Ei, U, E4);
  k_wdft<<<2048, 256, 0, stream>>>(x, Eo, Ei, T);
  k_hdft<<<1024, 256, 0, stream>>>(T, U, Xp);
  k_mix<<<512, 256, 0, stream>>>(Xp, wr, wi, Yp);
  k_hidft<<<1024, 256, 0, stream>>>(Yp, U, G);
  k_widft<<<2048, 256, 0, stream>>>(G, E4, out);
}